// Round 5
// baseline (207.082 us; speedup 1.0000x reference)
//
#include <hip/hip_runtime.h>

// PSAMask collect: out[(nh*97+nw)*9409 + h*97 + w] = x[(nh-h+48)*97 + (nw-w+48)][h][w]
// (valid window, else 0). Pure permutation -> memory-bound.
//
// Block = (nh, h-chunk of 6..7): per h, stage input plane a = nh-h+48 into LDS
// (global_load_lds DMA), then write one h-row of all 97 (nh,nw) channels.
// Each output channel gets a contiguous TH*388B run owned by this block.
// LDS is source-swizzled: lds[b*97 + (w+b)%97] = x[b][w], so the diagonal
// read b = nw-w+48 has lane-to-lane bank delta -1 -> conflict-free unpadded.
//
// R5 change (tests H10, TCC fetch-on-partial-write): output stores are
// NONTEMPORAL (nt) -> no write-allocate fetch of output lines from HBM.
// Predicted -300+ MB HBM fetch if H10 holds.

#define HW    97
#define PLANE 9409       // 97*97
#define HALF  48
#define NT    512
#define NITER 19         // ceil(9409/512); 9409 = 18*512 + 193

typedef const __attribute__((address_space(1))) void* gptr_t;
typedef __attribute__((address_space(3))) void* lptr_t;

__global__ __launch_bounds__(NT)
void psamask_collect_kernel(const float* __restrict__ x, float* __restrict__ out) {
    const int nh = blockIdx.x;          // 0..96
    const int c  = blockIdx.y;          // 0..15  (h-chunks: sizes 7,6,6,...,6)
    const int h0 = (c == 0) ? 0 : 7 + (c - 1) * 6;
    const int TH = (c == 0) ? 7 : 6;
    const unsigned tid = threadIdx.x;

    const unsigned r0 = tid / HW;       // 0..5
    const unsigned c0 = tid - r0 * HW;

    __shared__ float lds[PLANE];        // 36,836 B -> 4 blocks/CU

    for (int t = 0; t < TH; ++t) {
        const int h = h0 + t;
        const int a = nh - h + HALF;
        const bool avalid = ((unsigned)a < HW);

        if (t) __syncthreads();         // prev row's LDS reads done before overwrite

        // ---- stage plane (a fixed, all b,w): lds[b*97 + (w+b)%97] = xp[b*PLANE + w]
        if (avalid) {
            const float* __restrict__ xp =
                x + (size_t)((unsigned)a * HW) * PLANE + (unsigned)h * HW;
            unsigned b = r0, cw = c0;   // flat dest d = b*97 + cw
            #pragma unroll
            for (int k = 0; k < NITER; ++k) {
                unsigned d = tid + (unsigned)k * NT;
                if (d < PLANE) {
                    unsigned w = cw - b + ((cw < b) ? HW : 0u);   // (cw-b) mod 97
                    const float* g = xp + b * PLANE + w;          // per-lane source
                    unsigned d0 = (unsigned)k * NT + (tid & ~63u); // wave-uniform dest
                    __builtin_amdgcn_global_load_lds((gptr_t)g, (lptr_t)&lds[d0], 4, 0, 0);
                }
                b += 5; cw += 27;        // 512 = 5*97 + 27
                if (cw >= HW) { cw -= HW; b += 1; }
            }
        }
        asm volatile("s_waitcnt vmcnt(0)" ::: "memory");
        __syncthreads();

        // ---- write row h of all channels: outp[nw*PLANE + w]  (nontemporal)
        {
            float* __restrict__ outp =
                out + (size_t)((unsigned)nh * HW) * PLANE + (unsigned)h * HW;
            unsigned w   = c0;
            int      b   = (int)r0 - (int)c0 + HALF;             // nw - w + 48
            unsigned cw  = r0 + HALF; if (cw >= HW) cw -= HW;    // (nw+48) % 97
            unsigned off = r0 * PLANE + c0;
            #pragma unroll
            for (int k = 0; k < NITER; ++k) {
                unsigned d = tid + (unsigned)k * NT;
                if (d < PLANE) {
                    bool valid = avalid && ((unsigned)b < HW);
                    unsigned bc = ((unsigned)b < HW) ? (unsigned)b : 0u;
                    float v = lds[bc * HW + cw];
                    __builtin_nontemporal_store(valid ? v : 0.0f, &outp[off]);
                }
                w += 27;
                bool wrap = (w >= HW);
                if (wrap) w -= HW;
                b  += wrap ? 76 : -22;
                cw += wrap ? 6u : 5u;
                if (cw >= HW) cw -= HW;
                off += wrap ? (6u * PLANE - 70u) : (5u * PLANE + 27u);
            }
        }
    }
}

extern "C" void kernel_launch(void* const* d_in, const int* in_sizes, int n_in,
                              void* d_out, int out_size, void* d_ws, size_t ws_size,
                              hipStream_t stream) {
    const float* x = (const float*)d_in[0];
    float* out = (float*)d_out;
    dim3 grid(HW, 16);   // (nh, h-chunk)
    psamask_collect_kernel<<<grid, NT, 0, stream>>>(x, out);
}

// Round 6
// 166.958 us; speedup vs baseline: 1.2403x; 1.2403x over previous
//
#include <hip/hip_runtime.h>

// PSAMask collect: out[(nh*97+nw)*9409 + h*97 + w] = x[(nh-h+48)*97 + (nw-w+48)][h][w]
// (valid window, else 0). Pure permutation -> memory-bound.
//
// R6 (tests H11, DRAM time-coherence of write granules): block = (nh, h-PAIR).
// Both planes (a0=nh-h0+48, h0) and (a0-1, h0+1) staged into LDS together
// (75.3 KB -> 2 blocks/CU), ONE vmcnt(0) drain, then each channel's 776 B
// 2-row run is written by consecutive lanes/instructions -> seam sectors
// combine in L2, write bursts double. Grid = (chunk, nh) so co-resident
// blocks write a contiguous ~74 MB output window (DRAM row locality).
// LDS source-swizzled per plane: lds[p][b*97 + (w+b)%97] = x[b][w] ->
// diagonal read delta -97 -> bank delta -1 -> conflict-free.

#define HW    97
#define PLANE 9409      // 97*97
#define HALF  48
#define NT    512
#define NITER 19        // ceil(PLANE/NT); 9409 = 18*512 + 193
#define RUN   194       // 2*97 floats per channel run
#define TOT2  18818     // 2*PLANE
#define WITER 37        // ceil(TOT2/NT); 18818 = 36*512 + 386

typedef const __attribute__((address_space(1))) void* gptr_t;
typedef __attribute__((address_space(3))) void* lptr_t;

__global__ __launch_bounds__(NT)
void psamask_collect_kernel(const float* __restrict__ x, float* __restrict__ out) {
    const int c  = blockIdx.x;          // 0..48 (h-pairs; c=48 is the single row h=96)
    const int nh = blockIdx.y;          // 0..96
    const int h0 = 2 * c;
    const int TH = (h0 == 96) ? 1 : 2;
    const unsigned tid = threadIdx.x;

    const unsigned r0 = tid / HW;       // 0..5
    const unsigned c0 = tid - r0 * HW;

    __shared__ float lds[2 * PLANE];    // 75,272 B -> 2 blocks/CU

    const int a0 = nh - h0 + HALF;
    const bool av0 = ((unsigned)a0 < HW);
    const bool av1 = (TH == 2) && ((unsigned)(a0 - 1) < HW);

    // ---- stage up to 2 planes (async DMA, source-swizzled), single drain
    #pragma unroll
    for (int p = 0; p < 2; ++p) {
        const bool av = p ? av1 : av0;
        if (!av) continue;
        const float* __restrict__ xp =
            x + (size_t)((unsigned)(a0 - p) * HW) * PLANE + (unsigned)(h0 + p) * HW;
        unsigned b = r0, cw = c0;        // flat dest d = b*97 + cw
        #pragma unroll
        for (int k = 0; k < NITER; ++k) {
            unsigned d = tid + (unsigned)k * NT;
            if (d < PLANE) {
                unsigned w = cw - b + ((cw < b) ? HW : 0u);       // (cw-b) mod 97
                const float* g = xp + b * PLANE + w;              // per-lane source
                unsigned d0 = (unsigned)p * PLANE + (unsigned)k * NT + (tid & ~63u);
                __builtin_amdgcn_global_load_lds((gptr_t)g, (lptr_t)&lds[d0], 4, 0, 0);
            }
            b += 5; cw += 27;            // 512 = 5*97 + 27
            if (cw >= HW) { cw -= HW; b += 1; }
        }
    }
    asm volatile("s_waitcnt vmcnt(0)" ::: "memory");
    __syncthreads();

    float* __restrict__ outp =
        out + (size_t)((unsigned)nh * HW) * PLANE + (unsigned)h0 * HW;

    if (TH == 2) {
        // elements p = q*194 + e over all 97 channels' contiguous 2-row runs
        unsigned q  = (tid >= RUN ? 1u : 0u) + (tid >= 2u * RUN ? 1u : 0u);
        unsigned e  = tid - q * RUN;
        unsigned cw = q + HALF;                          // (q+48), q0<=2 so <97
        unsigned off = q * PLANE + e;
        #pragma unroll
        for (int k = 0; k < WITER; ++k) {
            unsigned d = tid + (unsigned)k * NT;
            if (d < TOT2) {
                unsigned hp = (e >= HW) ? 1u : 0u;       // which plane/row
                unsigned w  = e - hp * HW;
                int b = (int)q - (int)w + HALF;          // nw - w + 48
                bool vb = ((unsigned)b < HW);
                unsigned bc = vb ? (unsigned)b : 0u;
                float v = lds[hp * PLANE + bc * HW + cw];
                bool av = hp ? av1 : av0;
                outp[off] = (vb && av) ? v : 0.0f;
            }
            // p += 512 = 2*194 + 124
            e += 124u; q += 2u; cw += 2u; off += 2u * PLANE + 124u;
            if (e >= RUN) { e -= RUN; q += 1u; cw += 1u; off += PLANE - RUN; }
            if (cw >= HW) cw -= HW;
        }
    } else {
        // last chunk: single row h = 96 (R4-style write)
        unsigned w   = c0;
        int      b   = (int)r0 - (int)c0 + HALF;
        unsigned cw  = r0 + HALF; if (cw >= HW) cw -= HW;
        unsigned off = r0 * PLANE + c0;
        #pragma unroll
        for (int k = 0; k < NITER; ++k) {
            unsigned d = tid + (unsigned)k * NT;
            if (d < PLANE) {
                bool vb = ((unsigned)b < HW);
                unsigned bc = vb ? (unsigned)b : 0u;
                float v = lds[bc * HW + cw];
                outp[off] = (vb && av0) ? v : 0.0f;
            }
            w += 27;
            bool wrap = (w >= HW);
            if (wrap) w -= HW;
            b  += wrap ? 76 : -22;
            cw += wrap ? 6u : 5u;
            if (cw >= HW) cw -= HW;
            off += wrap ? (6u * PLANE - 70u) : (5u * PLANE + 27u);
        }
    }
}

extern "C" void kernel_launch(void* const* d_in, const int* in_sizes, int n_in,
                              void* d_out, int out_size, void* d_ws, size_t ws_size,
                              hipStream_t stream) {
    const float* x = (const float*)d_in[0];
    float* out = (float*)d_out;
    dim3 grid(49, HW);   // (h-pair chunk, nh): co-resident blocks share an output window
    psamask_collect_kernel<<<grid, NT, 0, stream>>>(x, out);
}